// Round 22
// baseline (444.995 us; speedup 1.0000x reference)
//
#include <hip/hip_runtime.h>
#include <hip/hip_bf16.h>
#include <hip/hip_fp16.h>
#include <math.h>

// Problem constants
#define B_   256
#define HID_ 1024
#define SP_  2048
#define N_   196        // 14*14
#define NJ_  (B_ * N_)  // 50176 = 196 * 256
#define SPB_ (SP_ * N_) // elems per batch of spatial

typedef float    f32x4 __attribute__((ext_vector_type(4)));
typedef _Float16 f16x8 __attribute__((ext_vector_type(8)));

#define GLOBAL_AS(p) ((const __attribute__((address_space(1))) void*)(p))
#define LDS_AS(p)    ((__attribute__((address_space(3))) void*)(p))

__device__ __forceinline__ float fast_tanh(float x) {
    const float e = exp2f(x * 2.8853900817779268f);  // 2*log2(e)
    return 1.f - 2.f / (e + 1.f);
}

// ---------------------------------------------------------------------------
// K1a (split-h): h1p[hq][b][d] = sum_{h in quarter hq} hidden[b,h] * W1[h,d]
// ---------------------------------------------------------------------------
__global__ __launch_bounds__(256) void k1_h1p(
    const float* __restrict__ hidden, const float* __restrict__ W1,
    float* __restrict__ h1p)
{
    __shared__ float hs[4][256];
    const int t  = threadIdx.x;
    const int d  = blockIdx.x * 256 + t;
    const int b0 = blockIdx.y * 4;
    const int h0 = blockIdx.z * 256;

    for (int i = t; i < 4 * 256; i += 256)
        hs[i >> 8][i & 255] = hidden[(size_t)(b0 + (i >> 8)) * HID_ + h0 + (i & 255)];
    __syncthreads();

    float acc[4] = {};
    for (int h = 0; h < 256; ++h) {
        const float w = W1[(size_t)(h0 + h) * HID_ + d];
#pragma unroll
        for (int i = 0; i < 4; ++i) acc[i] += hs[i][h] * w;
    }
#pragma unroll
    for (int i = 0; i < 4; ++i)
        h1p[((size_t)blockIdx.z * B_ + b0 + i) * HID_ + d] = acc[i];
}

// K1b: h1[bd] = sum_hq h1p[hq][bd] + b1[d]   (deterministic reduce)
__global__ __launch_bounds__(256) void k1_reduce(
    const float* __restrict__ h1p, const float* __restrict__ b1,
    float* __restrict__ h1)
{
    const size_t idx = (size_t)blockIdx.x * 256 + threadIdx.x;  // < 262144
    const int d = idx & (HID_ - 1);
    float s = b1[d];
#pragma unroll
    for (int hq = 0; hq < 4; ++hq)
        s += h1p[(size_t)hq * B_ * HID_ + idx];
    h1[idx] = s;
}

// ---------------------------------------------------------------------------
// K1 (monolithic, fallback path only)
// ---------------------------------------------------------------------------
__global__ __launch_bounds__(256) void k1_h1(
    const float* __restrict__ hidden, const float* __restrict__ W1,
    const float* __restrict__ b1, float* __restrict__ h1)
{
    __shared__ float hs[4][HID_];
    const int t = threadIdx.x;
    const int d = blockIdx.x * 256 + t;
    const int b0 = blockIdx.y * 4;

    for (int i = t; i < 4 * HID_; i += 256)
        hs[i >> 10][i & 1023] = hidden[(size_t)(b0 + (i >> 10)) * HID_ + (i & 1023)];
    __syncthreads();

    float acc[4] = {};
    for (int h = 0; h < HID_; ++h) {
        const float w = W1[(size_t)h * HID_ + d];
#pragma unroll
        for (int i = 0; i < 4; ++i) acc[i] += hs[i][h] * w;
    }
    const float bias = b1[d];
#pragma unroll
    for (int i = 0; i < 4; ++i)
        h1[(size_t)(b0 + i) * HID_ + d] = acc[i] + bias;
}

// ---------------------------------------------------------------------------
// K0a (coalesced): pack A = W1s^T into fp16 chunks.
// Chunk (dt, ks): 128 d x 32 c, layout [cg(4)][dd(128)][c8(8)] = 4096 halfs.
// ---------------------------------------------------------------------------
__global__ __launch_bounds__(256) void k0a_packA(
    const float* __restrict__ W1, __half* __restrict__ Ah)
{
    const int idx = blockIdx.x * 256 + threadIdx.x;   // < 262144
    const int dd = idx & 127;
    const int cg = (idx >> 7) & 3;
    const int ks = (idx >> 9) & 63;
    const int dt = idx >> 15;                          // 0..7
    const int d  = dt * 128 + dd;
    const int c0 = ks * 32 + cg * 8;

    f16x8 v;
#pragma unroll
    for (int c8 = 0; c8 < 8; ++c8)
        v[c8] = (_Float16)W1[(size_t)(HID_ + c0 + c8) * HID_ + d];
    *(f16x8*)(Ah + ((size_t)(dt * 64 + ks)) * 4096 + cg * 1024 + dd * 8) = v;
}

// ---------------------------------------------------------------------------
// K0b (float4): pack B = spT into fp16 chunks.
// ---------------------------------------------------------------------------
__global__ __launch_bounds__(256) void k0b_packB(
    const float* __restrict__ spatial, __half* __restrict__ Bh)
{
    const int jt2 = blockIdx.x;           // 0..195
    const int ks  = blockIdx.y;           // 0..63
    const int t   = threadIdx.x;
    const int cg  = t >> 6;               // 0..3
    const int jg  = t & 63;               // 0..63 (4 j's each)

    const int j0 = jt2 * 256 + jg * 4;
    const int b  = j0 / N_;               // uniform across the 4 j's
    const int n0 = j0 - b * N_;
    const float* src = spatial + (size_t)b * SPB_
                     + (size_t)(ks * 32 + cg * 8) * N_ + n0;

    f16x8 v[4];
#pragma unroll
    for (int c8 = 0; c8 < 8; ++c8) {
        const float4 f = *(const float4*)(src + (size_t)c8 * N_);
        v[0][c8] = (_Float16)f.x;
        v[1][c8] = (_Float16)f.y;
        v[2][c8] = (_Float16)f.z;
        v[3][c8] = (_Float16)f.w;
    }
    __half* outb = Bh + (((size_t)jt2 * 64 + ks) * 4 + cg) * 2048 + jg * 32;
#pragma unroll
    for (int q = 0; q < 4; ++q)
        *(f16x8*)(outb + q * 8) = v[q];
}

// ---------------------------------------------------------------------------
// K2 (v5: 2-slot dbuf, 1 barrier/step, 3 blocks/CU): 128d x 256j block tile,
// 4 waves (2Mx2N), per-wave 64x128, BK=32, full K=2048.
// 2-slot ring = 48 KB STATIC -> 3 blocks/CU (12 waves, +50% TLP vs R19).
// Per step: vmcnt(0)+barrier at START (drains stage issued one full step ago
// -> nearly free), then {ds_read af,bf | STAGE_A(kt+1)} -> 16 MFMA ->
// {ds_read bf2 | STAGE_B(kt+1)} -> 16 MFMA. ONE barrier/step (64 vs 128).
// WAR: STAGE(kt+1 -> S^1) writes the slot whose reads finished before this
// step's entry barrier. Single-barrier steps let waves skew phases (T5).
// ---------------------------------------------------------------------------
__global__ __launch_bounds__(256, 2) void k2_pipe(
    const __half* __restrict__ Ah, const __half* __restrict__ Bh,
    const float* __restrict__ W2, const float* __restrict__ h1,
    float* __restrict__ ps)
{
    __shared__ __align__(16) short ldsb[2 * 12288];   // 48 KB static

    const int tid = threadIdx.x;
    const int l  = tid & 63;
    const int w  = tid >> 6;            // wave 0..3
    const int wm = w >> 1;              // 0..1  (d half: 64 rows)
    const int wn = w & 1;               // 0..1  (j half: 128 cols)
    const int cg = l >> 4;              // 0..3
    const int rr = l & 15;

    // bijective XCD-chunked swizzle: 1568 = 8 * 196; dt fastest in chunk.
    const int orig = blockIdx.x;
    const int wgid = (orig & 7) * 196 + (orig >> 3);
    const int jt2 = wgid >> 3;          // 0..195
    const int dt  = wgid & 7;           // 0..7

    const __half* apack = Ah + ((size_t)dt * 64) * 4096;
    const __half* bpack = Bh + ((size_t)jt2 * 64) * 8192;

    f32x4 acc[4][8] = {};

#define STAGE_A(KT, SLOT) do {                                                  \
        const __half* as_ = apack + (size_t)(KT) * 4096;                        \
        short* ad_ = ldsb + (SLOT) * 12288 + w * 1024;                          \
        __builtin_amdgcn_global_load_lds(GLOBAL_AS(as_ + w * 1024 + l * 8),     \
                                         LDS_AS(ad_), 16, 0, 0);                \
        __builtin_amdgcn_global_load_lds(GLOBAL_AS(as_ + w * 1024 + 512 + l * 8),\
                                         LDS_AS(ad_ + 512), 16, 0, 0);          \
    } while (0)

#define STAGE_B(KT, SLOT) do {                                                  \
        const __half* bs_ = bpack + (size_t)(KT) * 8192;                        \
        short* bd_ = ldsb + (SLOT) * 12288 + 4096 + w * 2048;                   \
        _Pragma("unroll")                                                       \
        for (int i_ = 0; i_ < 4; ++i_)                                          \
            __builtin_amdgcn_global_load_lds(                                   \
                GLOBAL_AS(bs_ + w * 2048 + i_ * 512 + l * 8),                   \
                LDS_AS(bd_ + i_ * 512), 16, 0, 0);                              \
    } while (0)

#define STEP(KT, CSLOT, SSLOT, DO_STAGE) do {                                   \
        asm volatile("s_waitcnt vmcnt(0)" ::: "memory");                        \
        __builtin_amdgcn_s_barrier();                                           \
        const short* ab_ = ldsb + (CSLOT) * 12288;                              \
        const short* bb_ = ab_ + 4096;                                          \
        f16x8 af[4], bf[4], bf2[4];                                             \
        _Pragma("unroll")                                                       \
        for (int mi = 0; mi < 4; ++mi)                                          \
            af[mi] = *(const f16x8*)&ab_[(cg * 128 + wm * 64 + mi * 16 + rr) * 8];\
        _Pragma("unroll")                                                       \
        for (int ni = 0; ni < 4; ++ni)                                          \
            bf[ni] = *(const f16x8*)&bb_[(cg * 256 + wn * 128 + ni * 16 + rr) * 8];\
        if (DO_STAGE) STAGE_A((KT) + 1, SSLOT);                                 \
        asm volatile("s_waitcnt lgkmcnt(0)" ::: "memory");                      \
        __builtin_amdgcn_sched_barrier(0);                                      \
        __builtin_amdgcn_s_setprio(1);                                          \
        _Pragma("unroll")                                                       \
        for (int mi = 0; mi < 4; ++mi)                                          \
            _Pragma("unroll")                                                   \
            for (int ni = 0; ni < 4; ++ni)                                      \
                acc[mi][ni] = __builtin_amdgcn_mfma_f32_16x16x32_f16(           \
                    af[mi], bf[ni], acc[mi][ni], 0, 0, 0);                      \
        __builtin_amdgcn_s_setprio(0);                                          \
        _Pragma("unroll")                                                       \
        for (int ni = 0; ni < 4; ++ni)                                          \
            bf2[ni] = *(const f16x8*)&bb_[(cg * 256 + wn * 128 + (ni + 4) * 16 + rr) * 8];\
        if (DO_STAGE) STAGE_B((KT) + 1, SSLOT);                                 \
        asm volatile("s_waitcnt lgkmcnt(0)" ::: "memory");                      \
        __builtin_amdgcn_sched_barrier(0);                                      \
        __builtin_amdgcn_s_setprio(1);                                          \
        _Pragma("unroll")                                                       \
        for (int mi = 0; mi < 4; ++mi)                                          \
            _Pragma("unroll")                                                   \
            for (int ni = 0; ni < 4; ++ni)                                      \
                acc[mi][ni + 4] = __builtin_amdgcn_mfma_f32_16x16x32_f16(       \
                    af[mi], bf2[ni], acc[mi][ni + 4], 0, 0, 0);                 \
        __builtin_amdgcn_s_setprio(0);                                          \
    } while (0)

    // prologue: stage step 0 into slot 0
    STAGE_A(0, 0);
    STAGE_B(0, 0);

#pragma unroll 1
    for (int kt = 0; kt < 62; kt += 2) {
        STEP(kt + 0, 0, 1, true);
        STEP(kt + 1, 1, 0, true);
    }
    STEP(62, 0, 1, true);   // stages 63 -> slot 1
    STEP(63, 1, 0, false);

#undef STAGE_A
#undef STAGE_B
#undef STEP

    // Epilogue: partial[j] = sum_{d in this block's 128} tanh(acc + h1) * w2
    const int dbase = dt * 128 + wm * 64;
    float w2v[4][4];
#pragma unroll
    for (int mi = 0; mi < 4; ++mi)
#pragma unroll
        for (int q = 0; q < 4; ++q)
            w2v[mi][q] = W2[dbase + mi * 16 + cg * 4 + q];

    float partial[8];
#pragma unroll
    for (int ni = 0; ni < 8; ++ni) {
        const int j = jt2 * 256 + wn * 128 + ni * 16 + rr;
        const int bj = j / N_;
        const float* h1p = h1 + (size_t)bj * HID_ + dbase;
        float s = 0.f;
#pragma unroll
        for (int mi = 0; mi < 4; ++mi)
#pragma unroll
            for (int q = 0; q < 4; ++q)
                s += fast_tanh(acc[mi][ni][q] + h1p[mi * 16 + cg * 4 + q]) * w2v[mi][q];
        partial[ni] = s;
    }

    float* red = (float*)ldsb;
    __syncthreads();                 // all waves done with ring LDS reads
    red[tid] = 0.f;
    __syncthreads();
#pragma unroll
    for (int ni = 0; ni < 8; ++ni)
        atomicAdd(&red[wn * 128 + ni * 16 + rr], partial[ni]);
    __syncthreads();
    ps[(size_t)dt * NJ_ + (size_t)jt2 * 256 + tid] = red[tid];
}

// ---------------------------------------------------------------------------
// K2 fallback (fp32 vector path) if workspace is too small for packing.
// ---------------------------------------------------------------------------
__global__ __launch_bounds__(256) void k2_fb(
    const float* __restrict__ spatial, const float* __restrict__ W1,
    const float* __restrict__ W2, const float* __restrict__ h1,
    float* __restrict__ ps)
{
    __shared__ float As[32][64];
    __shared__ float Bs[32][64];
    const int t = threadIdx.x;
    const int d0 = blockIdx.x * 64;
    const int j0 = blockIdx.y * 64;
    const int ld = t & 63, lk = t >> 6;
    const float* Aptr = W1 + (size_t)(HID_ + lk) * HID_ + (d0 + ld);
    const int j = j0 + ld;
    const int bb = j / N_, nn = j - bb * N_;
    const float* Bptr = spatial + (size_t)bb * SPB_ + (size_t)lk * N_ + nn;
    const int tr = t >> 4, tc = t & 15;
    float acc[4][4] = {};
    for (int c0 = 0; c0 < SP_; c0 += 32) {
#pragma unroll
        for (int i = 0; i < 8; ++i) {
            As[lk + 4 * i][ld] = Aptr[(size_t)(c0 + 4 * i) * HID_];
            Bs[lk + 4 * i][ld] = Bptr[(size_t)(c0 + 4 * i) * N_];
        }
        __syncthreads();
#pragma unroll
        for (int k = 0; k < 32; ++k) {
            float av[4], bv[4];
            *(float4*)av = *(const float4*)&As[k][tr * 4];
            *(float4*)bv = *(const float4*)&Bs[k][tc * 4];
#pragma unroll
            for (int di = 0; di < 4; ++di)
#pragma unroll
                for (int ji = 0; ji < 4; ++ji)
                    acc[di][ji] += av[di] * bv[ji];
        }
        __syncthreads();
    }
    float w2v[4];
#pragma unroll
    for (int di = 0; di < 4; ++di) w2v[di] = W2[d0 + tr * 4 + di];
    float partial[4] = {};
#pragma unroll
    for (int ji = 0; ji < 4; ++ji) {
        const int jg = j0 + tc * 4 + ji;
        const int bj = jg / N_;
        const float* h1row = h1 + (size_t)bj * HID_ + d0 + tr * 4;
#pragma unroll
        for (int di = 0; di < 4; ++di)
            partial[ji] += tanhf(acc[di][ji] + h1row[di]) * w2v[di];
    }
    __shared__ float red[64];
    if (t < 64) red[t] = 0.f;
    __syncthreads();
#pragma unroll
    for (int ji = 0; ji < 4; ++ji)
        atomicAdd(&red[tc * 4 + ji], partial[ji]);
    __syncthreads();
    if (t < 64)
        ps[(size_t)blockIdx.x * NJ_ + j0 + t] = red[t];
}

// ---------------------------------------------------------------------------
// K3: scores[b,n] = sum_slices ps; attn = softmax_n  (b2 shift-invariant)
// ---------------------------------------------------------------------------
__global__ __launch_bounds__(256) void k3_softmax(
    const float* __restrict__ ps, float* __restrict__ attn, int nslices)
{
    const int b = blockIdx.x;
    const int t = threadIdx.x;
    __shared__ float sdata[256];

    float s = -1e30f;
    if (t < N_) {
        s = 0.f;
        for (int dt = 0; dt < nslices; ++dt)
            s += ps[(size_t)dt * NJ_ + b * N_ + t];
    }
    sdata[t] = s;
    __syncthreads();
    for (int off = 128; off > 0; off >>= 1) {
        if (t < off) sdata[t] = fmaxf(sdata[t], sdata[t + off]);
        __syncthreads();
    }
    const float m = sdata[0];
    __syncthreads();
    const float e = (t < N_) ? expf(s - m) : 0.f;
    sdata[t] = e;
    __syncthreads();
    for (int off = 128; off > 0; off >>= 1) {
        if (t < off) sdata[t] += sdata[t + off];
        __syncthreads();
    }
    const float inv = 1.f / sdata[0];
    if (t < N_) attn[(size_t)b * N_ + t] = e * inv;
}

// ---------------------------------------------------------------------------
// K4: context from the fp16 pack Bh — half the traffic of fp32 spatial.
// ---------------------------------------------------------------------------
__global__ __launch_bounds__(256) void k4_ctx_bh(
    const __half* __restrict__ Bh, const float* __restrict__ attn,
    float* __restrict__ ctx)
{
    const int wid  = blockIdx.x * 4 + (threadIdx.x >> 6);  // 0..65535
    const int lane = threadIdx.x & 63;
    const int b  = wid >> 8;          // 0..255
    const int sub = wid & 255;
    const int ks = sub >> 2;          // 0..63
    const int cg = sub & 3;           // 0..3

    const float* at = attn + (size_t)b * N_;
    const int jbase = b * N_;         // j of n=0

    float p[8] = {};
#pragma unroll
    for (int it = 0; it < 4; ++it) {
        const int n = it * 64 + lane;
        if (n < N_) {
            const int j = jbase + n;
            const int jt2 = j >> 8;
            const int jj  = j & 255;
            const f16x8 v = *(const f16x8*)(Bh +
                ((((size_t)jt2 * 64 + ks) * 4 + cg) * 2048) + jj * 8);
            const float a = at[n];
#pragma unroll
            for (int q = 0; q < 8; ++q)
                p[q] += a * (float)v[q];
        }
    }
#pragma unroll
    for (int off = 32; off > 0; off >>= 1)
#pragma unroll
        for (int q = 0; q < 8; ++q)
            p[q] += __shfl_down(p[q], off, 64);

    if (lane == 0) {
        float* out = ctx + (size_t)b * 2048 + ks * 32 + cg * 8;
#pragma unroll
        for (int q = 0; q < 8; ++q) out[q] = p[q];
    }
}

// ---------------------------------------------------------------------------
// K4 fallback (fp32 path)
// ---------------------------------------------------------------------------
__global__ __launch_bounds__(256) void k4_context(
    const float* __restrict__ spatial, const float* __restrict__ attn,
    float* __restrict__ ctx)
{
    const int wid = (blockIdx.x * 256 + threadIdx.x) >> 6;
    const int lane = threadIdx.x & 63;
    const int b = wid >> 11;
    const int c = wid & 2047;
    const float* sp = spatial + (size_t)b * SPB_ + (size_t)c * N_;
    const float* at = attn + (size_t)b * N_;

    float sum = 0.f;
    if (lane < 49) {
        const float4 s4 = ((const float4*)sp)[lane];
        const float4 a4 = ((const float4*)at)[lane];
        sum = s4.x * a4.x + s4.y * a4.y + s4.z * a4.z + s4.w * a4.w;
    }
#pragma unroll
    for (int off = 32; off > 0; off >>= 1)
        sum += __shfl_down(sum, off, 64);
    if (lane == 0)
        ctx[(size_t)b * 2048 + c] = sum;
}

// ---------------------------------------------------------------------------
extern "C" void kernel_launch(void* const* d_in, const int* in_sizes, int n_in,
                              void* d_out, int out_size, void* d_ws, size_t ws_size,
                              hipStream_t stream)
{
    const float* hidden  = (const float*)d_in[0];
    const float* spatial = (const float*)d_in[1];
    const float* W1      = (const float*)d_in[2];
    const float* b1      = (const float*)d_in[3];
    const float* W2      = (const float*)d_in[4];
    // b2 unused: softmax shift-invariant.

    float* out_ctx  = (float*)d_out;
    float* out_attn = (float*)d_out + (size_t)B_ * 2048;

    char* ws = (char*)d_ws;
    float* h1  = (float*)ws;                              // 1 MB
    float* psb = (float*)(ws + (1u << 20));               // 8 slices (1.6 MB)
    float* h1p = (float*)(ws + (4u << 20));               // 4 MB (4x256x1024)

    // MFMA-path workspace layout
    const size_t offAh = 8u << 20;                         // 4 MB
    const size_t offBh = 16u << 20;                        // 205 MB
    const size_t szB   = (size_t)196 * 64 * 8192 * 2;      // 205,520,896 B
    const size_t needed = offBh + szB;                     // ~212 MB

    if (ws_size >= needed) {
        __half* Ah = (__half*)(ws + offAh);
        __half* Bh = (__half*)(ws + offBh);
        k1_h1p<<<dim3(4, 64, 4), 256, 0, stream>>>(hidden, W1, h1p);
        k1_reduce<<<dim3(1024), 256, 0, stream>>>(h1p, b1, h1);
        k0a_packA<<<dim3(1024), 256, 0, stream>>>(W1, Ah);
        k0b_packB<<<dim3(196, 64), 256, 0, stream>>>(spatial, Bh);
        k2_pipe<<<dim3(1568), 256, 0, stream>>>(Ah, Bh, W2, h1, psb);
        k3_softmax<<<dim3(B_), 256, 0, stream>>>(psb, out_attn, 8);
        k4_ctx_bh<<<dim3(16384), 256, 0, stream>>>(Bh, out_attn, out_ctx);
    } else {
        k1_h1<<<dim3(4, 64), 256, 0, stream>>>(hidden, W1, b1, h1);
        k2_fb<<<dim3(16, 784), 256, 0, stream>>>(spatial, W1, W2, h1, psb);
        k3_softmax<<<dim3(B_), 256, 0, stream>>>(psb, out_attn, 16);
        k4_context<<<dim3((B_ * 2048) / 4), 256, 0, stream>>>(spatial, out_attn, out_ctx);
    }
}

// Round 23
// 414.778 us; speedup vs baseline: 1.0729x; 1.0729x over previous
//
#include <hip/hip_runtime.h>
#include <hip/hip_bf16.h>
#include <hip/hip_fp16.h>
#include <math.h>

// Problem constants
#define B_   256
#define HID_ 1024
#define SP_  2048
#define N_   196        // 14*14
#define NJ_  (B_ * N_)  // 50176 = 196 * 256
#define SPB_ (SP_ * N_) // elems per batch of spatial

typedef float    f32x4 __attribute__((ext_vector_type(4)));
typedef _Float16 f16x8 __attribute__((ext_vector_type(8)));

#define GLOBAL_AS(p) ((const __attribute__((address_space(1))) void*)(p))
#define LDS_AS(p)    ((__attribute__((address_space(3))) void*)(p))

__device__ __forceinline__ float fast_tanh(float x) {
    const float e = exp2f(x * 2.8853900817779268f);  // 2*log2(e)
    return 1.f - 2.f / (e + 1.f);
}

// ---------------------------------------------------------------------------
// K1a (split-h): h1p[hq][b][d] = sum_{h in quarter hq} hidden[b,h] * W1[h,d]
// ---------------------------------------------------------------------------
__global__ __launch_bounds__(256) void k1_h1p(
    const float* __restrict__ hidden, const float* __restrict__ W1,
    float* __restrict__ h1p)
{
    __shared__ float hs[4][256];
    const int t  = threadIdx.x;
    const int d  = blockIdx.x * 256 + t;
    const int b0 = blockIdx.y * 4;
    const int h0 = blockIdx.z * 256;

    for (int i = t; i < 4 * 256; i += 256)
        hs[i >> 8][i & 255] = hidden[(size_t)(b0 + (i >> 8)) * HID_ + h0 + (i & 255)];
    __syncthreads();

    float acc[4] = {};
    for (int h = 0; h < 256; ++h) {
        const float w = W1[(size_t)(h0 + h) * HID_ + d];
#pragma unroll
        for (int i = 0; i < 4; ++i) acc[i] += hs[i][h] * w;
    }
#pragma unroll
    for (int i = 0; i < 4; ++i)
        h1p[((size_t)blockIdx.z * B_ + b0 + i) * HID_ + d] = acc[i];
}

// K1b: h1[bd] = sum_hq h1p[hq][bd] + b1[d]   (deterministic reduce)
__global__ __launch_bounds__(256) void k1_reduce(
    const float* __restrict__ h1p, const float* __restrict__ b1,
    float* __restrict__ h1)
{
    const size_t idx = (size_t)blockIdx.x * 256 + threadIdx.x;  // < 262144
    const int d = idx & (HID_ - 1);
    float s = b1[d];
#pragma unroll
    for (int hq = 0; hq < 4; ++hq)
        s += h1p[(size_t)hq * B_ * HID_ + idx];
    h1[idx] = s;
}

// ---------------------------------------------------------------------------
// K1 (monolithic, fallback path only)
// ---------------------------------------------------------------------------
__global__ __launch_bounds__(256) void k1_h1(
    const float* __restrict__ hidden, const float* __restrict__ W1,
    const float* __restrict__ b1, float* __restrict__ h1)
{
    __shared__ float hs[4][HID_];
    const int t = threadIdx.x;
    const int d = blockIdx.x * 256 + t;
    const int b0 = blockIdx.y * 4;

    for (int i = t; i < 4 * HID_; i += 256)
        hs[i >> 10][i & 1023] = hidden[(size_t)(b0 + (i >> 10)) * HID_ + (i & 1023)];
    __syncthreads();

    float acc[4] = {};
    for (int h = 0; h < HID_; ++h) {
        const float w = W1[(size_t)h * HID_ + d];
#pragma unroll
        for (int i = 0; i < 4; ++i) acc[i] += hs[i][h] * w;
    }
    const float bias = b1[d];
#pragma unroll
    for (int i = 0; i < 4; ++i)
        h1[(size_t)(b0 + i) * HID_ + d] = acc[i] + bias;
}

// ---------------------------------------------------------------------------
// K0a (coalesced): pack A = W1s^T into fp16 chunks.
// Chunk (dt, ks): 128 d x 32 c, layout [cg(4)][dd(128)][c8(8)] = 4096 halfs.
// ---------------------------------------------------------------------------
__global__ __launch_bounds__(256) void k0a_packA(
    const float* __restrict__ W1, __half* __restrict__ Ah)
{
    const int idx = blockIdx.x * 256 + threadIdx.x;   // < 262144
    const int dd = idx & 127;
    const int cg = (idx >> 7) & 3;
    const int ks = (idx >> 9) & 63;
    const int dt = idx >> 15;                          // 0..7
    const int d  = dt * 128 + dd;
    const int c0 = ks * 32 + cg * 8;

    f16x8 v;
#pragma unroll
    for (int c8 = 0; c8 < 8; ++c8)
        v[c8] = (_Float16)W1[(size_t)(HID_ + c0 + c8) * HID_ + d];
    *(f16x8*)(Ah + ((size_t)(dt * 64 + ks)) * 4096 + cg * 1024 + dd * 8) = v;
}

// ---------------------------------------------------------------------------
// K0b (float4): pack B = spT into fp16 chunks.
// ---------------------------------------------------------------------------
__global__ __launch_bounds__(256) void k0b_packB(
    const float* __restrict__ spatial, __half* __restrict__ Bh)
{
    const int jt2 = blockIdx.x;           // 0..195
    const int ks  = blockIdx.y;           // 0..63
    const int t   = threadIdx.x;
    const int cg  = t >> 6;               // 0..3
    const int jg  = t & 63;               // 0..63 (4 j's each)

    const int j0 = jt2 * 256 + jg * 4;
    const int b  = j0 / N_;               // uniform across the 4 j's
    const int n0 = j0 - b * N_;
    const float* src = spatial + (size_t)b * SPB_
                     + (size_t)(ks * 32 + cg * 8) * N_ + n0;

    f16x8 v[4];
#pragma unroll
    for (int c8 = 0; c8 < 8; ++c8) {
        const float4 f = *(const float4*)(src + (size_t)c8 * N_);
        v[0][c8] = (_Float16)f.x;
        v[1][c8] = (_Float16)f.y;
        v[2][c8] = (_Float16)f.z;
        v[3][c8] = (_Float16)f.w;
    }
    __half* outb = Bh + (((size_t)jt2 * 64 + ks) * 4 + cg) * 2048 + jg * 32;
#pragma unroll
    for (int q = 0; q < 4; ++q)
        *(f16x8*)(outb + q * 8) = v[q];
}

// ---------------------------------------------------------------------------
// K2 (best-measured, R18/R19/R21): 128d x 256j block tile, 4 waves (2Mx2N).
// 3-slot LDS ring (72 KB dynamic) -> 2 blocks/CU. BK=32, full K=2048.
// Per-step two phases split by ni: P0 reads af[0..3]+bf[0..3] (8) -> 16 MFMA
// acc[*][0..3]; P1 reads bf2[0..3] (4, af reused) -> 16 MFMA acc[*][4..7].
// Counted vmcnt(6), stage-ahead-2. 235 µs / 42.5% MfmaUtil measured.
// ---------------------------------------------------------------------------
__global__ __launch_bounds__(256, 2) void k2_pipe(
    const __half* __restrict__ Ah, const __half* __restrict__ Bh,
    const float* __restrict__ W2, const float* __restrict__ h1,
    float* __restrict__ ps)
{
    extern __shared__ __align__(16) short ldsb[];   // 3 * 12288 halfs = 72 KB

    const int tid = threadIdx.x;
    const int l  = tid & 63;
    const int w  = tid >> 6;            // wave 0..3
    const int wm = w >> 1;              // 0..1  (d half: 64 rows)
    const int wn = w & 1;               // 0..1  (j half: 128 cols)
    const int cg = l >> 4;              // 0..3
    const int rr = l & 15;

    // bijective XCD-chunked swizzle: 1568 = 8 * 196; dt fastest in chunk.
    const int orig = blockIdx.x;
    const int wgid = (orig & 7) * 196 + (orig >> 3);
    const int jt2 = wgid >> 3;          // 0..195
    const int dt  = wgid & 7;           // 0..7

    const __half* apack = Ah + ((size_t)dt * 64) * 4096;
    const __half* bpack = Bh + ((size_t)jt2 * 64) * 8192;

    f32x4 acc[4][8] = {};

#define STAGE_A(KT, SLOT) do {                                                  \
        const __half* as_ = apack + (size_t)(KT) * 4096;                        \
        short* ad_ = ldsb + (SLOT) * 12288 + w * 1024;                          \
        __builtin_amdgcn_global_load_lds(GLOBAL_AS(as_ + w * 1024 + l * 8),     \
                                         LDS_AS(ad_), 16, 0, 0);                \
        __builtin_amdgcn_global_load_lds(GLOBAL_AS(as_ + w * 1024 + 512 + l * 8),\
                                         LDS_AS(ad_ + 512), 16, 0, 0);          \
    } while (0)

#define STAGE_B(KT, SLOT) do {                                                  \
        const __half* bs_ = bpack + (size_t)(KT) * 8192;                        \
        short* bd_ = ldsb + (SLOT) * 12288 + 4096 + w * 2048;                   \
        _Pragma("unroll")                                                       \
        for (int i_ = 0; i_ < 4; ++i_)                                          \
            __builtin_amdgcn_global_load_lds(                                   \
                GLOBAL_AS(bs_ + w * 2048 + i_ * 512 + l * 8),                   \
                LDS_AS(bd_ + i_ * 512), 16, 0, 0);                              \
    } while (0)

#define STEP(KT, CSLOT, SSLOT, DO_STAGE, VMC) do {                              \
        const short* ab_ = ldsb + (CSLOT) * 12288;                              \
        const short* bb_ = ab_ + 4096;                                          \
        f16x8 af[4], bf[4], bf2[4];                                             \
        _Pragma("unroll")                                                       \
        for (int mi = 0; mi < 4; ++mi)                                          \
            af[mi] = *(const f16x8*)&ab_[(cg * 128 + wm * 64 + mi * 16 + rr) * 8];\
        _Pragma("unroll")                                                       \
        for (int ni = 0; ni < 4; ++ni)                                          \
            bf[ni] = *(const f16x8*)&bb_[(cg * 256 + wn * 128 + ni * 16 + rr) * 8];\
        if (DO_STAGE) STAGE_A((KT) + 2, SSLOT);                                 \
        __builtin_amdgcn_s_barrier();                                           \
        asm volatile("s_waitcnt lgkmcnt(0)" ::: "memory");                      \
        __builtin_amdgcn_sched_barrier(0);                                      \
        __builtin_amdgcn_s_setprio(1);                                          \
        _Pragma("unroll")                                                       \
        for (int mi = 0; mi < 4; ++mi)                                          \
            _Pragma("unroll")                                                   \
            for (int ni = 0; ni < 4; ++ni)                                      \
                acc[mi][ni] = __builtin_amdgcn_mfma_f32_16x16x32_f16(           \
                    af[mi], bf[ni], acc[mi][ni], 0, 0, 0);                      \
        __builtin_amdgcn_s_setprio(0);                                          \
        _Pragma("unroll")                                                       \
        for (int ni = 0; ni < 4; ++ni)                                          \
            bf2[ni] = *(const f16x8*)&bb_[(cg * 256 + wn * 128 + (ni + 4) * 16 + rr) * 8];\
        if (DO_STAGE) STAGE_B((KT) + 2, SSLOT);                                 \
        asm volatile("s_waitcnt vmcnt(" #VMC ")" ::: "memory");                 \
        __builtin_amdgcn_s_barrier();                                           \
        asm volatile("s_waitcnt lgkmcnt(0)" ::: "memory");                      \
        __builtin_amdgcn_sched_barrier(0);                                      \
        __builtin_amdgcn_s_setprio(1);                                          \
        _Pragma("unroll")                                                       \
        for (int mi = 0; mi < 4; ++mi)                                          \
            _Pragma("unroll")                                                   \
            for (int ni = 0; ni < 4; ++ni)                                      \
                acc[mi][ni + 4] = __builtin_amdgcn_mfma_f32_16x16x32_f16(       \
                    af[mi], bf2[ni], acc[mi][ni + 4], 0, 0, 0);                 \
        __builtin_amdgcn_s_setprio(0);                                          \
    } while (0)

    // prologue: stage slots 0,1 fully; confirm slot 0
    STAGE_A(0, 0); STAGE_B(0, 0);
    STAGE_A(1, 1); STAGE_B(1, 1);
    asm volatile("s_waitcnt vmcnt(6)" ::: "memory");
    __builtin_amdgcn_s_barrier();

#pragma unroll 1
    for (int kt = 0; kt < 60; kt += 3) {
        STEP(kt + 0, 0, 2, true, 6);
        STEP(kt + 1, 1, 0, true, 6);
        STEP(kt + 2, 2, 1, true, 6);
    }
    STEP(60, 0, 2, true, 6);   // stages 62 -> slot 2
    STEP(61, 1, 0, true, 6);   // stages 63 -> slot 0; vmcnt(6) confirms 62
    STEP(62, 2, 0, false, 0);  // vmcnt(0) confirms 63
    STEP(63, 0, 0, false, 0);

#undef STAGE_A
#undef STAGE_B
#undef STEP

    // Epilogue: partial[j] = sum_{d in this block's 128} tanh(acc + h1) * w2
    const int dbase = dt * 128 + wm * 64;
    float w2v[4][4];
#pragma unroll
    for (int mi = 0; mi < 4; ++mi)
#pragma unroll
        for (int q = 0; q < 4; ++q)
            w2v[mi][q] = W2[dbase + mi * 16 + cg * 4 + q];

    float partial[8];
#pragma unroll
    for (int ni = 0; ni < 8; ++ni) {
        const int j = jt2 * 256 + wn * 128 + ni * 16 + rr;
        const int bj = j / N_;
        const float* h1p = h1 + (size_t)bj * HID_ + dbase;
        float s = 0.f;
#pragma unroll
        for (int mi = 0; mi < 4; ++mi)
#pragma unroll
            for (int q = 0; q < 4; ++q)
                s += fast_tanh(acc[mi][ni][q] + h1p[mi * 16 + cg * 4 + q]) * w2v[mi][q];
        partial[ni] = s;
    }

    float* red = (float*)ldsb;
    __syncthreads();                 // all waves done with ring LDS reads
    red[tid] = 0.f;
    __syncthreads();
#pragma unroll
    for (int ni = 0; ni < 8; ++ni)
        atomicAdd(&red[wn * 128 + ni * 16 + rr], partial[ni]);
    __syncthreads();
    ps[(size_t)dt * NJ_ + (size_t)jt2 * 256 + tid] = red[tid];
}

// ---------------------------------------------------------------------------
// K2 fallback (fp32 vector path) if workspace is too small for packing.
// ---------------------------------------------------------------------------
__global__ __launch_bounds__(256) void k2_fb(
    const float* __restrict__ spatial, const float* __restrict__ W1,
    const float* __restrict__ W2, const float* __restrict__ h1,
    float* __restrict__ ps)
{
    __shared__ float As[32][64];
    __shared__ float Bs[32][64];
    const int t = threadIdx.x;
    const int d0 = blockIdx.x * 64;
    const int j0 = blockIdx.y * 64;
    const int ld = t & 63, lk = t >> 6;
    const float* Aptr = W1 + (size_t)(HID_ + lk) * HID_ + (d0 + ld);
    const int j = j0 + ld;
    const int bb = j / N_, nn = j - bb * N_;
    const float* Bptr = spatial + (size_t)bb * SPB_ + (size_t)lk * N_ + nn;
    const int tr = t >> 4, tc = t & 15;
    float acc[4][4] = {};
    for (int c0 = 0; c0 < SP_; c0 += 32) {
#pragma unroll
        for (int i = 0; i < 8; ++i) {
            As[lk + 4 * i][ld] = Aptr[(size_t)(c0 + 4 * i) * HID_];
            Bs[lk + 4 * i][ld] = Bptr[(size_t)(c0 + 4 * i) * N_];
        }
        __syncthreads();
#pragma unroll
        for (int k = 0; k < 32; ++k) {
            float av[4], bv[4];
            *(float4*)av = *(const float4*)&As[k][tr * 4];
            *(float4*)bv = *(const float4*)&Bs[k][tc * 4];
#pragma unroll
            for (int di = 0; di < 4; ++di)
#pragma unroll
                for (int ji = 0; ji < 4; ++ji)
                    acc[di][ji] += av[di] * bv[ji];
        }
        __syncthreads();
    }
    float w2v[4];
#pragma unroll
    for (int di = 0; di < 4; ++di) w2v[di] = W2[d0 + tr * 4 + di];
    float partial[4] = {};
#pragma unroll
    for (int ji = 0; ji < 4; ++ji) {
        const int jg = j0 + tc * 4 + ji;
        const int bj = jg / N_;
        const float* h1row = h1 + (size_t)bj * HID_ + d0 + tr * 4;
#pragma unroll
        for (int di = 0; di < 4; ++di)
            partial[ji] += tanhf(acc[di][ji] + h1row[di]) * w2v[di];
    }
    __shared__ float red[64];
    if (t < 64) red[t] = 0.f;
    __syncthreads();
#pragma unroll
    for (int ji = 0; ji < 4; ++ji)
        atomicAdd(&red[tc * 4 + ji], partial[ji]);
    __syncthreads();
    if (t < 64)
        ps[(size_t)blockIdx.x * NJ_ + j0 + t] = red[t];
}

// ---------------------------------------------------------------------------
// K3: scores[b,n] = sum_slices ps; attn = softmax_n  (b2 shift-invariant)
// ---------------------------------------------------------------------------
__global__ __launch_bounds__(256) void k3_softmax(
    const float* __restrict__ ps, float* __restrict__ attn, int nslices)
{
    const int b = blockIdx.x;
    const int t = threadIdx.x;
    __shared__ float sdata[256];

    float s = -1e30f;
    if (t < N_) {
        s = 0.f;
        for (int dt = 0; dt < nslices; ++dt)
            s += ps[(size_t)dt * NJ_ + b * N_ + t];
    }
    sdata[t] = s;
    __syncthreads();
    for (int off = 128; off > 0; off >>= 1) {
        if (t < off) sdata[t] = fmaxf(sdata[t], sdata[t + off]);
        __syncthreads();
    }
    const float m = sdata[0];
    __syncthreads();
    const float e = (t < N_) ? expf(s - m) : 0.f;
    sdata[t] = e;
    __syncthreads();
    for (int off = 128; off > 0; off >>= 1) {
        if (t < off) sdata[t] += sdata[t + off];
        __syncthreads();
    }
    const float inv = 1.f / sdata[0];
    if (t < N_) attn[(size_t)b * N_ + t] = e * inv;
}

// ---------------------------------------------------------------------------
// K4: context from the fp16 pack Bh — half the traffic of fp32 spatial.
// ---------------------------------------------------------------------------
__global__ __launch_bounds__(256) void k4_ctx_bh(
    const __half* __restrict__ Bh, const float* __restrict__ attn,
    float* __restrict__ ctx)
{
    const int wid  = blockIdx.x * 4 + (threadIdx.x >> 6);  // 0..65535
    const int lane = threadIdx.x & 63;
    const int b  = wid >> 8;          // 0..255
    const int sub = wid & 255;
    const int ks = sub >> 2;          // 0..63
    const int cg = sub & 3;           // 0..3

    const float* at = attn + (size_t)b * N_;
    const int jbase = b * N_;         // j of n=0

    float p[8] = {};
#pragma unroll
    for (int it = 0; it < 4; ++it) {
        const int n = it * 64 + lane;
        if (n < N_) {
            const int j = jbase + n;
            const int jt2 = j >> 8;
            const int jj  = j & 255;
            const f16x8 v = *(const f16x8*)(Bh +
                ((((size_t)jt2 * 64 + ks) * 4 + cg) * 2048) + jj * 8);
            const float a = at[n];
#pragma unroll
            for (int q = 0; q < 8; ++q)
                p[q] += a * (float)v[q];
        }
    }
#pragma unroll
    for (int off = 32; off > 0; off >>= 1)
#pragma unroll
        for (int q = 0; q < 8; ++q)
            p[q] += __shfl_down(p[q], off, 64);

    if (lane == 0) {
        float* out = ctx + (size_t)b * 2048 + ks * 32 + cg * 8;
#pragma unroll
        for (int q = 0; q < 8; ++q) out[q] = p[q];
    }
}

// ---------------------------------------------------------------------------
// K4 fallback (fp32 path)
// ---------------------------------------------------------------------------
__global__ __launch_bounds__(256) void k4_context(
    const float* __restrict__ spatial, const float* __restrict__ attn,
    float* __restrict__ ctx)
{
    const int wid = (blockIdx.x * 256 + threadIdx.x) >> 6;
    const int lane = threadIdx.x & 63;
    const int b = wid >> 11;
    const int c = wid & 2047;
    const float* sp = spatial + (size_t)b * SPB_ + (size_t)c * N_;
    const float* at = attn + (size_t)b * N_;

    float sum = 0.f;
    if (lane < 49) {
        const float4 s4 = ((const float4*)sp)[lane];
        const float4 a4 = ((const float4*)at)[lane];
        sum = s4.x * a4.x + s4.y * a4.y + s4.z * a4.z + s4.w * a4.w;
    }
#pragma unroll
    for (int off = 32; off > 0; off >>= 1)
        sum += __shfl_down(sum, off, 64);
    if (lane == 0)
        ctx[(size_t)b * 2048 + c] = sum;
}

// ---------------------------------------------------------------------------
extern "C" void kernel_launch(void* const* d_in, const int* in_sizes, int n_in,
                              void* d_out, int out_size, void* d_ws, size_t ws_size,
                              hipStream_t stream)
{
    const float* hidden  = (const float*)d_in[0];
    const float* spatial = (const float*)d_in[1];
    const float* W1      = (const float*)d_in[2];
    const float* b1      = (const float*)d_in[3];
    const float* W2      = (const float*)d_in[4];
    // b2 unused: softmax shift-invariant.

    float* out_ctx  = (float*)d_out;
    float* out_attn = (float*)d_out + (size_t)B_ * 2048;

    char* ws = (char*)d_ws;
    float* h1  = (float*)ws;                              // 1 MB
    float* psb = (float*)(ws + (1u << 20));               // 8 slices (1.6 MB)
    float* h1p = (float*)(ws + (4u << 20));               // 4 MB (4x256x1024)

    // MFMA-path workspace layout
    const size_t offAh = 8u << 20;                         // 4 MB
    const size_t offBh = 16u << 20;                        // 205 MB
    const size_t szB   = (size_t)196 * 64 * 8192 * 2;      // 205,520,896 B
    const size_t needed = offBh + szB;                     // ~212 MB

    if (ws_size >= needed) {
        __half* Ah = (__half*)(ws + offAh);
        __half* Bh = (__half*)(ws + offBh);
        k1_h1p<<<dim3(4, 64, 4), 256, 0, stream>>>(hidden, W1, h1p);
        k1_reduce<<<dim3(1024), 256, 0, stream>>>(h1p, b1, h1);
        k0a_packA<<<dim3(1024), 256, 0, stream>>>(W1, Ah);
        k0b_packB<<<dim3(196, 64), 256, 0, stream>>>(spatial, Bh);
        (void)hipFuncSetAttribute((const void*)k2_pipe,
                                  hipFuncAttributeMaxDynamicSharedMemorySize,
                                  73728);
        k2_pipe<<<dim3(1568), 256, 73728, stream>>>(Ah, Bh, W2, h1, psb);
        k3_softmax<<<dim3(B_), 256, 0, stream>>>(psb, out_attn, 8);
        k4_ctx_bh<<<dim3(16384), 256, 0, stream>>>(Bh, out_attn, out_ctx);
    } else {
        k1_h1<<<dim3(4, 64), 256, 0, stream>>>(hidden, W1, b1, h1);
        k2_fb<<<dim3(16, 784), 256, 0, stream>>>(spatial, W1, W2, h1, psb);
        k3_softmax<<<dim3(B_), 256, 0, stream>>>(psb, out_attn, 16);
        k4_context<<<dim3((B_ * 2048) / 4), 256, 0, stream>>>(spatial, out_attn, out_ctx);
    }
}